// Round 2
// 2420.765 us; speedup vs baseline: 3.2793x; 3.2793x over previous
//
#include <hip/hip_runtime.h>
#include <math.h>

// Problem constants
#define Bb 64
#define Tt 1024
#define Dd 512
#define Hh 512

// ---------------------------------------------------------------------------
// Kernel 1: xw = x @ W[:D] + b   (M=65536, K=512, N=512), fp32.
// Unchanged (~470 us). Writes into d_out; scan overwrites in place.
// ---------------------------------------------------------------------------
#define TM 128
#define TN 128
#define TK 16
#define LDP (TN + 4)

__global__ __launch_bounds__(256) void gemm_xw(const float* __restrict__ x,
                                               const float* __restrict__ W,
                                               const float* __restrict__ bias,
                                               float* __restrict__ out) {
    __shared__ float As[TK][LDP];
    __shared__ float Bs[TK][LDP];

    const int tid = threadIdx.x;
    const int m0 = blockIdx.x * TM;
    const int n0 = blockIdx.y * TN;
    const int tx = tid & 15;
    const int ty = tid >> 4;

    float acc[8][8];
    #pragma unroll
    for (int i = 0; i < 8; i++)
        #pragma unroll
        for (int j = 0; j < 8; j++) acc[i][j] = 0.0f;

    for (int k0 = 0; k0 < Dd; k0 += TK) {
        #pragma unroll
        for (int i = 0; i < 2; i++) {
            const int idx = tid * 2 + i;
            const int r = idx >> 2;
            const int c = idx & 3;
            const float4 av = *(const float4*)(x + (size_t)(m0 + r) * Dd + k0 + c * 4);
            As[c * 4 + 0][r] = av.x;
            As[c * 4 + 1][r] = av.y;
            As[c * 4 + 2][r] = av.z;
            As[c * 4 + 3][r] = av.w;
            const int kk = idx >> 5;
            const int cg = (idx & 31) * 4;
            const float4 bv = *(const float4*)(W + (size_t)(k0 + kk) * Hh + n0 + cg);
            *(float4*)(&Bs[kk][cg]) = bv;
        }
        __syncthreads();

        #pragma unroll
        for (int kk = 0; kk < TK; kk++) {
            float a[8], b[8];
            #pragma unroll
            for (int i = 0; i < 8; i++) a[i] = As[kk][ty * 8 + i];
            #pragma unroll
            for (int j = 0; j < 8; j++) b[j] = Bs[kk][tx * 8 + j];
            #pragma unroll
            for (int i = 0; i < 8; i++)
                #pragma unroll
                for (int j = 0; j < 8; j++) acc[i][j] += a[i] * b[j];
        }
        __syncthreads();
    }

    #pragma unroll
    for (int i = 0; i < 8; i++) {
        const size_t row = (size_t)(m0 + ty * 8 + i) * Hh;
        const int n = n0 + tx * 8;
        float4 v0, v1;
        v0.x = acc[i][0] + bias[n + 0];
        v0.y = acc[i][1] + bias[n + 1];
        v0.z = acc[i][2] + bias[n + 2];
        v0.w = acc[i][3] + bias[n + 3];
        v1.x = acc[i][4] + bias[n + 4];
        v1.y = acc[i][5] + bias[n + 5];
        v1.z = acc[i][6] + bias[n + 6];
        v1.w = acc[i][7] + bias[n + 7];
        *(float4*)(out + row + n) = v0;
        *(float4*)(out + row + n + 4) = v1;
    }
}

// ---------------------------------------------------------------------------
// Kernel 2: scan, register-resident weights + self-tagged atomic exchange.
//
// Protocol (zero cache-wide maintenance ops — replaces R2's wbl2/inv storm):
//   - Publish: pack (tag=t+1, h-bits) into u64; RELAXED agent atomic store
//     (per-address coherent at the IC; no release fence, no wbl2).
//   - Consume: 384 partner threads spin (with s_sleep backoff) on their OWN
//     u64 until tag==t+1; detection and data arrive in the same load. No
//     acquire fence, no buffer_inv. Aligned 64b accesses don't tear.
//   - Parity double-buffer g_hbuf[row][t&1][512]: a producer only reaches
//     tag t+3 on a slot after consuming partners' t+2, which proves the
//     partners consumed its t+1 (skew across blocks is bounded at 1 step).
//
// Robustness (R1 container death post-mortem):
//   - Exchange buffer is a __device__ global (.bss, zero-initialized) — no
//     dependence on ws_size, no OOB risk, no memset node. Cross-replay
//     safety without reset: wants are exact-match tags; a slot's stale tag
//     from the previous replay is overwritten hundreds of times before its
//     value could ever match a want again.
//   - s_sleep(1) backoff in the spin (R2 had it; removing it risks TCC
//     starvation livelock).
//   - Dead-man switch: spin bounded at 2^18 iters; on timeout the block
//     sets an LDS flag and free-runs -> failed verification WITH counters
//     instead of a killed container.
//
// Weight residency: VGPR_Count=48 last round proves the compiler was
// re-streaming Wh from L2 every step (~256 KB/step/CU ~ 1.7 us/step).
// The asm keep-alive pins w4 (64 VGPRs) in registers; launch_bounds
// (1024,4) allows 128 VGPR = 4 waves/SIMD = 16 waves/CU, 1 block/CU,
// 256 blocks co-resident (capacity-exact).
// Weights stay fp32 (recurrence amplifies per-step noise ~3000x).
// ---------------------------------------------------------------------------
__device__ unsigned long long g_hbuf[(size_t)Bb * 2 * Hh];   // 512 KB .bss

__global__ __launch_bounds__(1024, 4) void scan_rnn(const float* __restrict__ W,
                                                    float* __restrict__ out) {
    const float* __restrict__ Wh = W + (size_t)Dd * Hh;   // (H, H) row-major
    const int r = blockIdx.x & 63;        // batch row
    const int c = blockIdx.x >> 6;        // column group, 0..3 (cols 128c..)
    const int tid = threadIdx.x;
    const int g = tid & 31;               // 4-col group within slice
    const int s = tid >> 5;               // k-slice, 0..31 (k in [16s,16s+16))

    float* rowbase = out + (size_t)r * Tt * Hh;
    unsigned long long* hrow = g_hbuf + (size_t)r * 2 * Hh;  // [2][512] u64

    __shared__ float hs[Hh];              // full h_{t-1}
    __shared__ float ps[32][128];         // partials [s][j_local]
    __shared__ int sdead;                 // dead-man flag

    // ---- load weight slice into registers: w4[kk] = Wh[16s+kk][128c+4g..+3]
    float4 w4[16];
    {
        const float4* wbase = (const float4*)(Wh + (size_t)(s * 16) * Hh) + (c * 32 + g);
        #pragma unroll
        for (int kk = 0; kk < 16; kk++) w4[kk] = wbase[(size_t)kk * 128];
    }
    // Opaque keep-alive: forbid rematerialization of the weight loads inside
    // the t-loop (compiler was sinking them -> L2 streaming every step).
    #pragma unroll
    for (int kk = 0; kk < 16; kk++)
        asm volatile("" : "+v"(w4[kk].x), "+v"(w4[kk].y), "+v"(w4[kk].z), "+v"(w4[kk].w));

    if (tid < Hh) hs[tid] = 0.0f;
    if (tid == 0) sdead = 0;
    __syncthreads();

    for (int t = 0; t < Tt; t++) {
        // A: prefetch xw for own columns (written by gemm_xw; L2-warm)
        float z = 0.0f;
        if (tid < 128) z = rowbase[(size_t)t * Hh + c * 128 + tid];

        // B: FMA phase — 64 MACs/thread from register weights + LDS h_{t-1}
        float4 acc; acc.x = acc.y = acc.z = acc.w = 0.0f;
        #pragma unroll
        for (int kq = 0; kq < 4; kq++) {
            const float4 hv = *(const float4*)&hs[s * 16 + kq * 4];
            const float4 a0 = w4[kq * 4 + 0];
            const float4 a1 = w4[kq * 4 + 1];
            const float4 a2 = w4[kq * 4 + 2];
            const float4 a3 = w4[kq * 4 + 3];
            acc.x += hv.x * a0.x; acc.y += hv.x * a0.y; acc.z += hv.x * a0.z; acc.w += hv.x * a0.w;
            acc.x += hv.y * a1.x; acc.y += hv.y * a1.y; acc.z += hv.y * a1.z; acc.w += hv.y * a1.w;
            acc.x += hv.z * a2.x; acc.y += hv.z * a2.y; acc.z += hv.z * a2.z; acc.w += hv.z * a2.w;
            acc.x += hv.w * a3.x; acc.y += hv.w * a3.y; acc.z += hv.w * a3.z; acc.w += hv.w * a3.w;
        }
        *(float4*)&ps[s][g * 4] = acc;
        __syncthreads();   // ps ready; all hs reads of h_{t-1} done

        if (tid < 128) {
            // C: finalize own 128 columns; publish ASAP (critical path)
            #pragma unroll
            for (int q = 0; q < 32; q++) z += ps[q][tid];
            const float hn = tanhf(z);
            if (t < Tt - 1) {
                const unsigned long long pkt =
                    ((unsigned long long)(unsigned)(t + 1) << 32) | __float_as_uint(hn);
                __hip_atomic_store(&hrow[(size_t)(t & 1) * Hh + c * 128 + tid], pkt,
                                   __ATOMIC_RELAXED, __HIP_MEMORY_SCOPE_AGENT);
                hs[c * 128 + tid] = hn;
            }
            rowbase[(size_t)t * Hh + c * 128 + tid] = hn;   // output (write-only)
        } else if (tid < 512 && t < Tt - 1) {
            // D: pull partners' h_t — spin on own tagged element
            const int p = (tid >> 7) - 1;            // 0..2
            const int cp = p + (p >= c ? 1 : 0);
            const int jj = tid & 127;
            unsigned long long* src = &hrow[(size_t)(t & 1) * Hh + cp * 128 + jj];
            const unsigned want = (unsigned)(t + 1);
            if (sdead == 0) {
                unsigned long long v;
                int spins = 0;
                for (;;) {
                    v = __hip_atomic_load(src, __ATOMIC_RELAXED, __HIP_MEMORY_SCOPE_AGENT);
                    if ((unsigned)(v >> 32) == want) break;
                    __builtin_amdgcn_s_sleep(1);
                    if (++spins > (1 << 18)) { sdead = 1; break; }   // dead-man
                }
                hs[cp * 128 + jj] = __uint_as_float((unsigned)v);
            }
        }
        __syncthreads();   // hs = full h_t
    }
}

// ---------------------------------------------------------------------------
extern "C" void kernel_launch(void* const* d_in, const int* in_sizes, int n_in,
                              void* d_out, int out_size, void* d_ws, size_t ws_size,
                              hipStream_t stream) {
    const float* x = (const float*)d_in[0];    // (B, T, D)
    const float* W = (const float*)d_in[1];    // (D+H, H)
    const float* b = (const float*)d_in[2];    // (H,)
    float* out = (float*)d_out;                // (B, T, H)
    (void)d_ws; (void)ws_size;

    dim3 ggrid((Bb * Tt) / TM, Hh / TN);       // 512 x 4
    gemm_xw<<<ggrid, dim3(256), 0, stream>>>(x, W, b, out);
    scan_rnn<<<dim3(256), dim3(1024), 0, stream>>>(W, out);
}